// Round 7
// baseline (543.118 us; speedup 1.0000x reference)
//
#include <hip/hip_runtime.h>
#include <hip/hip_fp16.h>
#include <math.h>

// Transformer-XL relative multi-head attention, MI355X. B=2,S=2048,D=512,H=8,dh=64.
// Round-7: Ppos ELIMINATED. The rel-shifted positional score is computed in-tile:
//   shifted[q][k] = qv[q]  . Pb[2047-(q-k)]   (k <= q)
//                 = 0                          (k == q+1)
//                 = qv[q+1]. Pb[k-q-2]         (k >= q+2)
// Per 16x128 tile both cases share local index ii = 15 - r + (k-k0) and need
// contiguous Pb row-ranges -> two small MFMA GEMMs (R1/R2) into wave-private LDS,
// then a ds_read_u16 + cndmask per element. No Ppos tensor, no pos_gemm, no
// scalar HBM gather; attention k-loop is fully L2/L3-resident.
//  1. proj_kernel (fp32): QU(+u)/QV(+v) fp16 [s][d]; K fp16 [s][d]; VT fp16 [d][s];
//     Pb fp16 [s][d].
//  2. attn_fused: block = 4 waves = 2 q-groups x 2 k-halves (split-K=2, one merge
//     barrier, otherwise barrier-free wave-autonomous; validated r6 structure).
//  3. out_gemm (fp32): out = ctx @ Wo + bo.

#define S_LEN 2048
#define NH 8
#define DHD 64
#define DM 512
#define NBH 16
#define HEAD_ELEMS (S_LEN * DHD)

// workspace byte offsets
#define BY_QU  0u               // fp16 [16][2048][64]  4 MB
#define BY_QV  4194304u         // fp16 [16][2048][64]  4 MB
#define BY_K   8388608u         // fp16 [16][2048][64]  4 MB
#define BY_VT  12582912u        // fp16 [16][64][2048]  4 MB
#define BY_PB  16777216u        // fp16 [16][2048][64]  4 MB
#define BY_CTX 20971520u        // fp32 [2][2048][512]  8 MB
#define WS_NEED 29360128u       // BY_CTX + 8 MB

typedef short v8s __attribute__((ext_vector_type(8)));
typedef float v4f __attribute__((ext_vector_type(4)));

static __device__ __forceinline__ unsigned short f2h(float f) {
    __half h = __float2half(f);
    return *reinterpret_cast<unsigned short*>(&h);
}
static __device__ __forceinline__ float h2f(unsigned short u) {
    __half h = *reinterpret_cast<__half*>(&u);
    return __half2float(h);
}

// ---------------------------------------------------------------------------
// Projections (fp32 compute): C[4096,512] = A @ W (+bias), mode via blockIdx.z.
// ---------------------------------------------------------------------------
__global__ __launch_bounds__(256)
void proj_kernel(const float* __restrict__ x, const float* __restrict__ pos,
                 const float* __restrict__ Wq, const float* __restrict__ bq,
                 const float* __restrict__ Wk, const float* __restrict__ bk,
                 const float* __restrict__ Wv, const float* __restrict__ bvp,
                 const float* __restrict__ Wp,
                 const float* __restrict__ uvec, const float* __restrict__ vvec,
                 char* __restrict__ wsb)
{
    __shared__ float Ast[32][132];
    __shared__ float Bs[32][132];
    const int t = threadIdx.x;
    const int tx = t & 15, ty = t >> 4;
    const int mode = blockIdx.z;
    const int n0 = blockIdx.x * 128, m0 = blockIdx.y * 128;

    const float* A = (mode == 3) ? pos : x;
    const float* W = (mode == 0) ? Wq : (mode == 1) ? Wk : (mode == 2) ? Wv : Wp;

    float acc[8][8];
#pragma unroll
    for (int i = 0; i < 8; ++i)
#pragma unroll
        for (int j = 0; j < 8; ++j) acc[i][j] = 0.f;

    for (int k0 = 0; k0 < 512; k0 += 32) {
#pragma unroll
        for (int i = 0; i < 4; ++i) {
            int f = t + i * 256;
            int row = f >> 3, kq = f & 7;
            float4 a4 = *(const float4*)(A + (size_t)(m0 + row) * 512 + k0 + kq * 4);
            Ast[kq * 4 + 0][row] = a4.x; Ast[kq * 4 + 1][row] = a4.y;
            Ast[kq * 4 + 2][row] = a4.z; Ast[kq * 4 + 3][row] = a4.w;
        }
#pragma unroll
        for (int i = 0; i < 4; ++i) {
            int f = t + i * 256;
            int row = f >> 5, c4 = f & 31;
            *(float4*)&Bs[row][c4 * 4] =
                *(const float4*)(W + (size_t)(k0 + row) * 512 + n0 + c4 * 4);
        }
        __syncthreads();
#pragma unroll
        for (int kc = 0; kc < 32; ++kc) {
            float a[8], b[8];
            *(float4*)&a[0] = *(const float4*)&Ast[kc][ty * 8];
            *(float4*)&a[4] = *(const float4*)&Ast[kc][ty * 8 + 4];
            *(float4*)&b[0] = *(const float4*)&Bs[kc][tx * 8];
            *(float4*)&b[4] = *(const float4*)&Bs[kc][tx * 8 + 4];
#pragma unroll
            for (int i = 0; i < 8; ++i)
#pragma unroll
                for (int j = 0; j < 8; ++j) acc[i][j] = fmaf(a[i], b[j], acc[i][j]);
        }
        __syncthreads();
    }

    const int bb = m0 >> 11;

    if (mode == 0) {
        unsigned short* qu = (unsigned short*)(wsb + BY_QU);
        unsigned short* qv = (unsigned short*)(wsb + BY_QV);
#pragma unroll
        for (int i = 0; i < 8; ++i) {
            int gm = m0 + ty * 8 + i, srow = gm & 2047;
#pragma unroll
            for (int j4 = 0; j4 < 2; ++j4) {
                int gn = n0 + tx * 8 + j4 * 4;
                int h = gn >> 6, d = gn & 63;
                float4 bi = *(const float4*)(bq + gn);
                float4 uu = *(const float4*)(uvec + gn);
                float4 vv = *(const float4*)(vvec + gn);
                float c0 = acc[i][j4 * 4 + 0] + bi.x, c1 = acc[i][j4 * 4 + 1] + bi.y;
                float c2 = acc[i][j4 * 4 + 2] + bi.z, c3 = acc[i][j4 * 4 + 3] + bi.w;
                size_t o = ((size_t)(bb * NH + h) * S_LEN + srow) * DHD + d;
                ushort4 pu, pv2;
                pu.x = f2h(c0 + uu.x); pu.y = f2h(c1 + uu.y);
                pu.z = f2h(c2 + uu.z); pu.w = f2h(c3 + uu.w);
                pv2.x = f2h(c0 + vv.x); pv2.y = f2h(c1 + vv.y);
                pv2.z = f2h(c2 + vv.z); pv2.w = f2h(c3 + vv.w);
                *(ushort4*)(qu + o) = pu;
                *(ushort4*)(qv + o) = pv2;
            }
        }
    } else if (mode == 1 || mode == 3) {   // K / Pb fp16 [bh][s][d]
        unsigned short* dst = (unsigned short*)(wsb + (mode == 1 ? BY_K : BY_PB));
        const float* bias = (mode == 1) ? bk : nullptr;
#pragma unroll
        for (int i = 0; i < 8; ++i) {
            int gm = m0 + ty * 8 + i, srow = gm & 2047;
#pragma unroll
            for (int j4 = 0; j4 < 2; ++j4) {
                int gn = n0 + tx * 8 + j4 * 4;
                int h = gn >> 6, d = gn & 63;
                float4 bi = bias ? *(const float4*)(bias + gn)
                                 : make_float4(0.f, 0.f, 0.f, 0.f);
                size_t o = ((size_t)(bb * NH + h) * S_LEN + srow) * DHD + d;
                ushort4 pk;
                pk.x = f2h(acc[i][j4 * 4 + 0] + bi.x);
                pk.y = f2h(acc[i][j4 * 4 + 1] + bi.y);
                pk.z = f2h(acc[i][j4 * 4 + 2] + bi.z);
                pk.w = f2h(acc[i][j4 * 4 + 3] + bi.w);
                *(ushort4*)(dst + o) = pk;
            }
        }
    } else {                               // VT fp16 [bh][d][s]
        unsigned short* vt = (unsigned short*)(wsb + BY_VT);
#pragma unroll
        for (int j = 0; j < 8; ++j) {
            int gn = n0 + tx * 8 + j;
            int h = gn >> 6, d = gn & 63;
            float bval = bvp[gn];
            size_t rowbase = ((size_t)(bb * NH + h) * DHD + d) * S_LEN;
#pragma unroll
            for (int i4 = 0; i4 < 2; ++i4) {
                int srow = (m0 & 2047) + ty * 8 + i4 * 4;
                ushort4 pk;
                pk.x = f2h(acc[i4 * 4 + 0][j] + bval);
                pk.y = f2h(acc[i4 * 4 + 1][j] + bval);
                pk.z = f2h(acc[i4 * 4 + 2][j] + bval);
                pk.w = f2h(acc[i4 * 4 + 3][j] + bval);
                *(ushort4*)(vt + rowbase + srow) = pk;
            }
        }
    }
}

// ---------------------------------------------------------------------------
// Fused flash attention with in-tile rel-shift GEMMs (split-K=2).
// Block 256 thr = 4 waves: wave = (kh = w>>1, qg = w&1). Wave owns q rows
// [qb*32+qg*16, +16) and keys [kh*1024, +1024), 8 k-tiles of 128; no barriers
// in the loop (wave-private LDS, in-order per wave).  End: one barrier + merge.
// mfma_f32_16x16x32_f16: A[m=l16][k=quad*8+j], B[k=quad*8+j][n=l16],
// C row=quad*4+reg col=l16 (validated r5/r6).
// LDS slot/wave: R1h 16x152 | R2h 16x152 (fp16); Sp (P-transpose 16x136) aliases
// R1h after its reads complete.  38.9 KB/block -> 4 blocks/CU.
// Pb over/under-reads (rows <0 or >2047, elements unused) stay inside d_ws.
// ---------------------------------------------------------------------------
__global__ __launch_bounds__(256, 4)
void attn_fused(const unsigned short* __restrict__ qu,
                const unsigned short* __restrict__ qvg,
                const unsigned short* __restrict__ kdat,
                const unsigned short* __restrict__ vtg,
                const unsigned short* __restrict__ pbg,
                float* __restrict__ ctx, int head_base)
{
    __shared__ unsigned short SpAll[4][4864];   // per-wave slot: 9728 B

    const int t = threadIdx.x;
    const int wave = t >> 6, lane = t & 63;
    const int quad = lane >> 4, l16 = lane & 15;
    const int qg = wave & 1, kh = wave >> 1;
    const int z = blockIdx.x >> 6, qb = blockIdx.x & 63;
    const int g = head_base + z;
    const int q0 = qb * 32 + qg * 16;

    const unsigned short* QU = qu   + (size_t)g * HEAD_ELEMS;   // [s][d]
    const unsigned short* QV = qvg  + (size_t)g * HEAD_ELEMS;   // [s][d]
    const unsigned short* Kg = kdat + (size_t)g * HEAD_ELEMS;   // [s][d]
    const unsigned short* Vg = vtg  + (size_t)g * HEAD_ELEMS;   // [d][s]
    const unsigned short* Pb = pbg  + (size_t)g * HEAD_ELEMS;   // [s][d]
    unsigned short* R1h = &SpAll[wave][0];       // 16 x 152
    unsigned short* R2h = &SpAll[wave][2432];    // 16 x 152
    unsigned short* Sp  = &SpAll[wave][0];       // 16 x 136, aliases R1h

    // loop-invariant A-fragments
    const v8s aq0 = *(const v8s*)(QU + (size_t)(q0 + l16) * DHD + quad * 8);
    const v8s aq1 = *(const v8s*)(QU + (size_t)(q0 + l16) * DHD + 32 + quad * 8);
    const v8s av0 = *(const v8s*)(QV + (size_t)(q0 + l16) * DHD + quad * 8);
    const v8s av1 = *(const v8s*)(QV + (size_t)(q0 + l16) * DHD + 32 + quad * 8);
    const v8s aw0 = *(const v8s*)(QV + (size_t)(q0 + 1 + l16) * DHD + quad * 8);
    const v8s aw1 = *(const v8s*)(QV + (size_t)(q0 + 1 + l16) * DHD + 32 + quad * 8);

    float m_run[4], l_run[4];
    v4f accv[4];
#pragma unroll
    for (int r = 0; r < 4; ++r) {
        m_run[r] = -1e30f; l_run[r] = 0.f;
        accv[r] = (v4f){0.f, 0.f, 0.f, 0.f};
    }
    const float scale = 0.04419417382415922f;   // 1/sqrt(512)

    for (int kt = 0; kt < 8; ++kt) {
        const int k0 = kh * 1024 + kt * 128;

        // QK^T: S[16 q][128 k]
        v4f sacc[8];
#pragma unroll
        for (int nt = 0; nt < 8; ++nt) {
            v8s b0 = *(const v8s*)(Kg + (size_t)(k0 + nt * 16 + l16) * DHD + quad * 8);
            v8s b1 = *(const v8s*)(Kg + (size_t)(k0 + nt * 16 + l16) * DHD + 32 + quad * 8);
            v4f c = (v4f){0.f, 0.f, 0.f, 0.f};
            c = __builtin_amdgcn_mfma_f32_16x16x32_f16(aq0, b0, c, 0, 0, 0);
            c = __builtin_amdgcn_mfma_f32_16x16x32_f16(aq1, b1, c, 0, 0, 0);
            sacc[nt] = c;
        }

        // R1[r][ii] = qv[q0+r] . Pb[J1+ii]   (covers k<=q elements)
        if (k0 <= q0 + 15) {
            const int J1 = 2032 - q0 + k0;
#pragma unroll
            for (int nt = 0; nt < 9; ++nt) {
                long row = (long)(J1 + nt * 16 + l16);
                v8s b0 = *(const v8s*)(Pb + row * DHD + quad * 8);
                v8s b1 = *(const v8s*)(Pb + row * DHD + 32 + quad * 8);
                v4f c = (v4f){0.f, 0.f, 0.f, 0.f};
                c = __builtin_amdgcn_mfma_f32_16x16x32_f16(av0, b0, c, 0, 0, 0);
                c = __builtin_amdgcn_mfma_f32_16x16x32_f16(av1, b1, c, 0, 0, 0);
#pragma unroll
                for (int reg = 0; reg < 4; ++reg)
                    R1h[(quad * 4 + reg) * 152 + nt * 16 + l16] = f2h(c[reg]);
            }
        }
        // R2[r][ii] = qv[q0+1+r] . Pb[J2+ii]  (covers k>=q+2 elements)
        if (k0 + 125 >= q0) {
            const int J2 = k0 - q0 - 17;
#pragma unroll
            for (int nt = 0; nt < 9; ++nt) {
                long row = (long)(J2 + nt * 16 + l16);
                v8s b0 = *(const v8s*)(Pb + row * DHD + quad * 8);
                v8s b1 = *(const v8s*)(Pb + row * DHD + 32 + quad * 8);
                v4f c = (v4f){0.f, 0.f, 0.f, 0.f};
                c = __builtin_amdgcn_mfma_f32_16x16x32_f16(aw0, b0, c, 0, 0, 0);
                c = __builtin_amdgcn_mfma_f32_16x16x32_f16(aw1, b1, c, 0, 0, 0);
#pragma unroll
                for (int reg = 0; reg < 4; ++reg)
                    R2h[(quad * 4 + reg) * 152 + nt * 16 + l16] = f2h(c[reg]);
            }
        }

        // add rel-shifted pos scores: ii = 15 - r + (k-k0); dq = k0-q0-15+ii
#pragma unroll
        for (int nt = 0; nt < 8; ++nt) {
#pragma unroll
            for (int reg = 0; reg < 4; ++reg) {
                int r = quad * 4 + reg;
                int ii = 15 - r + nt * 16 + l16;
                int dq = (k0 - q0) - 15 + ii;
                const unsigned short* Rb = (dq <= 0) ? R1h : R2h;
                float pv = h2f(Rb[r * 152 + ii]);
                sacc[nt][reg] += (dq == 1) ? 0.f : pv;
            }
        }

        // online softmax (row = quad*4+reg, 16 lanes x 8 nt cols)
#pragma unroll
        for (int reg = 0; reg < 4; ++reg) {
            float tm = -1e30f;
#pragma unroll
            for (int nt = 0; nt < 8; ++nt) {
                sacc[nt][reg] *= scale;
                tm = fmaxf(tm, sacc[nt][reg]);
            }
            tm = fmaxf(tm, __shfl_xor(tm, 1));
            tm = fmaxf(tm, __shfl_xor(tm, 2));
            tm = fmaxf(tm, __shfl_xor(tm, 4));
            tm = fmaxf(tm, __shfl_xor(tm, 8));
            float mn = fmaxf(m_run[reg], tm);
            float al = __expf(m_run[reg] - mn);
            float rs = 0.f;
#pragma unroll
            for (int nt = 0; nt < 8; ++nt) {
                sacc[nt][reg] = __expf(sacc[nt][reg] - mn);
                rs += sacc[nt][reg];
            }
            rs += __shfl_xor(rs, 1);
            rs += __shfl_xor(rs, 2);
            rs += __shfl_xor(rs, 4);
            rs += __shfl_xor(rs, 8);
            l_run[reg] = l_run[reg] * al + rs;
            m_run[reg] = mn;
#pragma unroll
            for (int ntd = 0; ntd < 4; ++ntd) accv[ntd][reg] *= al;
        }

        // P -> fp16 into wave-private Sp (aliases R1h; R1 reads are done), then PV
#pragma unroll
        for (int nt = 0; nt < 8; ++nt)
#pragma unroll
            for (int reg = 0; reg < 4; ++reg)
                Sp[(quad * 4 + reg) * 136 + nt * 16 + l16] = f2h(sacc[nt][reg]);

#pragma unroll
        for (int c4 = 0; c4 < 4; ++c4) {
            v8s ap = *(const v8s*)&Sp[l16 * 136 + c4 * 32 + quad * 8];
#pragma unroll
            for (int ntd = 0; ntd < 4; ++ntd) {
                v8s bv8 = *(const v8s*)(Vg + (size_t)(ntd * 16 + l16) * S_LEN +
                                        k0 + c4 * 32 + quad * 8);
                accv[ntd] = __builtin_amdgcn_mfma_f32_16x16x32_f16(ap, bv8, accv[ntd], 0, 0, 0);
            }
        }
    }

    // split-K merge: kh=1 dumps raw state into its slot (float view)
    if (kh == 1) {
        float* mb = (float*)&SpAll[wave][0];
#pragma unroll
        for (int ntd = 0; ntd < 4; ++ntd)
#pragma unroll
            for (int reg = 0; reg < 4; ++reg)
                mb[lane * 16 + ntd * 4 + reg] = accv[ntd][reg];
        if (l16 == 0) {
#pragma unroll
            for (int reg = 0; reg < 4; ++reg) {
                mb[1024 + (quad * 4 + reg) * 2]     = m_run[reg];
                mb[1024 + (quad * 4 + reg) * 2 + 1] = l_run[reg];
            }
        }
    }
    __syncthreads();
    if (kh == 0) {
        const float* mb = (const float*)&SpAll[2 + qg][0];
        const int bb = g >> 3, h = g & 7;
#pragma unroll
        for (int reg = 0; reg < 4; ++reg) {
            float m1 = mb[1024 + (quad * 4 + reg) * 2];
            float l1 = mb[1024 + (quad * 4 + reg) * 2 + 1];
            float mn = fmaxf(m_run[reg], m1);
            float a0 = __expf(m_run[reg] - mn);
            float a1 = __expf(m1 - mn);
            float inv = 1.f / (l_run[reg] * a0 + l1 * a1);
            int q = q0 + quad * 4 + reg;
#pragma unroll
            for (int ntd = 0; ntd < 4; ++ntd) {
                float o = (accv[ntd][reg] * a0 + mb[lane * 16 + ntd * 4 + reg] * a1) * inv;
                ctx[((size_t)(bb * S_LEN + q)) * DM + h * DHD + ntd * 16 + l16] = o;
            }
        }
    }
}

// ---------------------------------------------------------------------------
// Output GEMM: out[4096,512] = ctx @ Wo + bo (fp32)
// ---------------------------------------------------------------------------
__global__ __launch_bounds__(256)
void out_gemm(const float* __restrict__ ca,
              const float* __restrict__ Wo, const float* __restrict__ bo,
              float* __restrict__ out)
{
    __shared__ float Ast[32][132];
    __shared__ float Bs[32][132];
    const int t = threadIdx.x;
    const int tx = t & 15, ty = t >> 4;
    const int n0 = blockIdx.x * 128, m0 = blockIdx.y * 128;

    float acc[8][8];
#pragma unroll
    for (int i = 0; i < 8; ++i)
#pragma unroll
        for (int j = 0; j < 8; ++j) acc[i][j] = 0.f;

    for (int k0 = 0; k0 < 512; k0 += 32) {
#pragma unroll
        for (int i = 0; i < 4; ++i) {
            int f = t + i * 256;
            int row = f >> 3, kq = f & 7;
            float4 a4 = *(const float4*)(ca + (size_t)(m0 + row) * 512 + k0 + kq * 4);
            Ast[kq * 4 + 0][row] = a4.x; Ast[kq * 4 + 1][row] = a4.y;
            Ast[kq * 4 + 2][row] = a4.z; Ast[kq * 4 + 3][row] = a4.w;
        }
#pragma unroll
        for (int i = 0; i < 4; ++i) {
            int f = t + i * 256;
            int row = f >> 5, c4 = f & 31;
            *(float4*)&Bs[row][c4 * 4] =
                *(const float4*)(Wo + (size_t)(k0 + row) * 512 + n0 + c4 * 4);
        }
        __syncthreads();
#pragma unroll
        for (int kc = 0; kc < 32; ++kc) {
            float a[8], b[8];
            *(float4*)&a[0] = *(const float4*)&Ast[kc][ty * 8];
            *(float4*)&a[4] = *(const float4*)&Ast[kc][ty * 8 + 4];
            *(float4*)&b[0] = *(const float4*)&Bs[kc][tx * 8];
            *(float4*)&b[4] = *(const float4*)&Bs[kc][tx * 8 + 4];
#pragma unroll
            for (int i = 0; i < 8; ++i)
#pragma unroll
                for (int j = 0; j < 8; ++j) acc[i][j] = fmaf(a[i], b[j], acc[i][j]);
        }
        __syncthreads();
    }

#pragma unroll
    for (int i = 0; i < 8; ++i) {
        int gm = m0 + ty * 8 + i;
#pragma unroll
        for (int j4 = 0; j4 < 2; ++j4) {
            int gn = n0 + tx * 8 + j4 * 4;
            float4 bi = *(const float4*)(bo + gn);
            *(float4*)(out + (size_t)gm * 512 + gn) =
                make_float4(acc[i][j4 * 4 + 0] + bi.x, acc[i][j4 * 4 + 1] + bi.y,
                            acc[i][j4 * 4 + 2] + bi.z, acc[i][j4 * 4 + 3] + bi.w);
        }
    }
}

// Fallback when ws_size is insufficient: clean mismatch instead of OOB writes.
__global__ void zero_fill(float* __restrict__ p, int n)
{
    int i = blockIdx.x * 256 + threadIdx.x;
    if (i < n) p[i] = 0.f;
}

// ---------------------------------------------------------------------------
extern "C" void kernel_launch(void* const* d_in, const int* in_sizes, int n_in,
                              void* d_out, int out_size, void* d_ws, size_t ws_size,
                              hipStream_t stream)
{
    const float* x   = (const float*)d_in[0];
    const float* pos = (const float*)d_in[1];
    const float* Wq  = (const float*)d_in[2];
    const float* bq  = (const float*)d_in[3];
    const float* Wk  = (const float*)d_in[4];
    const float* bk  = (const float*)d_in[5];
    const float* Wv  = (const float*)d_in[6];
    const float* bv  = (const float*)d_in[7];
    const float* Wp  = (const float*)d_in[8];
    const float* u   = (const float*)d_in[9];
    const float* v   = (const float*)d_in[10];
    const float* Wo  = (const float*)d_in[11];
    const float* bo  = (const float*)d_in[12];
    char* wsb  = (char*)d_ws;
    float* out = (float*)d_out;

    if (ws_size < (size_t)WS_NEED) {
        zero_fill<<<(out_size + 255) / 256, 256, 0, stream>>>(out, out_size);
        return;
    }

    // 1. projections
    proj_kernel<<<dim3(4, 32, 4), 256, 0, stream>>>(x, pos, Wq, bq, Wk, bk, Wv, bv,
                                                    Wp, u, v, wsb);

    // 2. fused attention (all 16 heads, 64 q-blocks each)
    attn_fused<<<dim3(NBH * 64), 256, 0, stream>>>(
        (const unsigned short*)(wsb + BY_QU),
        (const unsigned short*)(wsb + BY_QV),
        (const unsigned short*)(wsb + BY_K),
        (const unsigned short*)(wsb + BY_VT),
        (const unsigned short*)(wsb + BY_PB),
        (float*)(wsb + BY_CTX), 0);

    // 3. output projection
    out_gemm<<<dim3(4, 32, 1), 256, 0, stream>>>((const float*)(wsb + BY_CTX),
                                                 Wo, bo, out);
}

// Round 8
// 472.970 us; speedup vs baseline: 1.1483x; 1.1483x over previous
//
#include <hip/hip_runtime.h>
#include <hip/hip_fp16.h>
#include <math.h>

// Transformer-XL relative multi-head attention, MI355X. B=2,S=2048,D=512,H=8,dh=64.
// Round-8: r6 structure, two fixes (r7 in-tile R-GEMMs reverted: scattered Pb rows
// + VGPR spill caused 392MB fetch / 242MB scratch writes):
//  a) pos_gemm scatter-stores PRE-SHIFTED Psh[q][k] (rel-shift bijection, r3-
//     validated; diagonal k=q+1 stays garbage, zeroed at use). Attn then reads
//     pos scores with ALIGNED vectorized loads.
//  b) attn_fused swaps MFMA operands (A=K, B=Q) so C puts q on lane&15:
//     - pos add = 8 aligned ushort4 loads/tile (vs 32 serialized scalars)
//     - softmax = per-lane reduce + 2 shuffles (vs 4), m/l scalar per lane
//     - P transpose = 8 ds_write_b64 (vs 32 scalar u16)
//     Split-K=4: block = 4 waves = 4 k-quarters of one 16-row q-tile; no barriers
//     in the k-loop (wave-private LDS slots); one end barrier + 4-way merge.
//  1. proj_kernel (fp32): QU(+u)/QV(+v) fp16 [s][d]; K fp16 [s][d]; VT fp16 [d][s];
//     Pb fp16 [s][d].
//  2. per head-chunk: pos_gemm -> Psh fp16; attn_fused -> ctx fp32.
//  3. out_gemm (fp32): out = ctx @ Wo + bo.

#define S_LEN 2048
#define NH 8
#define DHD 64
#define DM 512
#define NBH 16
#define HEAD_ELEMS (S_LEN * DHD)
#define SS ((size_t)S_LEN * (size_t)S_LEN)

// workspace byte offsets
#define BY_QU  0u               // fp16 [16][2048][64]  4 MB
#define BY_QV  4194304u         // fp16 [16][2048][64]  4 MB
#define BY_K   8388608u         // fp16 [16][2048][64]  4 MB
#define BY_VT  12582912u        // fp16 [16][64][2048]  4 MB
#define BY_PB  16777216u        // fp16 [16][2048][64]  4 MB
#define BY_CTX 20971520u        // fp32 [2][2048][512]  8 MB
#define BY_PSH 29360128u        // fp16 [c][2048][2048] 8.39 MB/head (shifted pos)
#define PSH_HEAD_BYTES 8388608u

typedef short v8s __attribute__((ext_vector_type(8)));
typedef float v4f __attribute__((ext_vector_type(4)));

static __device__ __forceinline__ unsigned short f2h(float f) {
    __half h = __float2half(f);
    return *reinterpret_cast<unsigned short*>(&h);
}
static __device__ __forceinline__ float h2f(unsigned short u) {
    __half h = *reinterpret_cast<__half*>(&u);
    return __half2float(h);
}

// ---------------------------------------------------------------------------
// Projections (fp32 compute): C[4096,512] = A @ W (+bias), mode via blockIdx.z.
// ---------------------------------------------------------------------------
__global__ __launch_bounds__(256)
void proj_kernel(const float* __restrict__ x, const float* __restrict__ pos,
                 const float* __restrict__ Wq, const float* __restrict__ bq,
                 const float* __restrict__ Wk, const float* __restrict__ bk,
                 const float* __restrict__ Wv, const float* __restrict__ bvp,
                 const float* __restrict__ Wp,
                 const float* __restrict__ uvec, const float* __restrict__ vvec,
                 char* __restrict__ wsb)
{
    __shared__ float Ast[32][132];
    __shared__ float Bs[32][132];
    const int t = threadIdx.x;
    const int tx = t & 15, ty = t >> 4;
    const int mode = blockIdx.z;
    const int n0 = blockIdx.x * 128, m0 = blockIdx.y * 128;

    const float* A = (mode == 3) ? pos : x;
    const float* W = (mode == 0) ? Wq : (mode == 1) ? Wk : (mode == 2) ? Wv : Wp;

    float acc[8][8];
#pragma unroll
    for (int i = 0; i < 8; ++i)
#pragma unroll
        for (int j = 0; j < 8; ++j) acc[i][j] = 0.f;

    for (int k0 = 0; k0 < 512; k0 += 32) {
#pragma unroll
        for (int i = 0; i < 4; ++i) {
            int f = t + i * 256;
            int row = f >> 3, kq = f & 7;
            float4 a4 = *(const float4*)(A + (size_t)(m0 + row) * 512 + k0 + kq * 4);
            Ast[kq * 4 + 0][row] = a4.x; Ast[kq * 4 + 1][row] = a4.y;
            Ast[kq * 4 + 2][row] = a4.z; Ast[kq * 4 + 3][row] = a4.w;
        }
#pragma unroll
        for (int i = 0; i < 4; ++i) {
            int f = t + i * 256;
            int row = f >> 5, c4 = f & 31;
            *(float4*)&Bs[row][c4 * 4] =
                *(const float4*)(W + (size_t)(k0 + row) * 512 + n0 + c4 * 4);
        }
        __syncthreads();
#pragma unroll
        for (int kc = 0; kc < 32; ++kc) {
            float a[8], b[8];
            *(float4*)&a[0] = *(const float4*)&Ast[kc][ty * 8];
            *(float4*)&a[4] = *(const float4*)&Ast[kc][ty * 8 + 4];
            *(float4*)&b[0] = *(const float4*)&Bs[kc][tx * 8];
            *(float4*)&b[4] = *(const float4*)&Bs[kc][tx * 8 + 4];
#pragma unroll
            for (int i = 0; i < 8; ++i)
#pragma unroll
                for (int j = 0; j < 8; ++j) acc[i][j] = fmaf(a[i], b[j], acc[i][j]);
        }
        __syncthreads();
    }

    const int bb = m0 >> 11;

    if (mode == 0) {
        unsigned short* qu = (unsigned short*)(wsb + BY_QU);
        unsigned short* qv = (unsigned short*)(wsb + BY_QV);
#pragma unroll
        for (int i = 0; i < 8; ++i) {
            int gm = m0 + ty * 8 + i, srow = gm & 2047;
#pragma unroll
            for (int j4 = 0; j4 < 2; ++j4) {
                int gn = n0 + tx * 8 + j4 * 4;
                int h = gn >> 6, d = gn & 63;
                float4 bi = *(const float4*)(bq + gn);
                float4 uu = *(const float4*)(uvec + gn);
                float4 vv = *(const float4*)(vvec + gn);
                float c0 = acc[i][j4 * 4 + 0] + bi.x, c1 = acc[i][j4 * 4 + 1] + bi.y;
                float c2 = acc[i][j4 * 4 + 2] + bi.z, c3 = acc[i][j4 * 4 + 3] + bi.w;
                size_t o = ((size_t)(bb * NH + h) * S_LEN + srow) * DHD + d;
                ushort4 pu, pv2;
                pu.x = f2h(c0 + uu.x); pu.y = f2h(c1 + uu.y);
                pu.z = f2h(c2 + uu.z); pu.w = f2h(c3 + uu.w);
                pv2.x = f2h(c0 + vv.x); pv2.y = f2h(c1 + vv.y);
                pv2.z = f2h(c2 + vv.z); pv2.w = f2h(c3 + vv.w);
                *(ushort4*)(qu + o) = pu;
                *(ushort4*)(qv + o) = pv2;
            }
        }
    } else if (mode == 1 || mode == 3) {   // K / Pb fp16 [bh][s][d]
        unsigned short* dst = (unsigned short*)(wsb + (mode == 1 ? BY_K : BY_PB));
        const float* bias = (mode == 1) ? bk : nullptr;
#pragma unroll
        for (int i = 0; i < 8; ++i) {
            int gm = m0 + ty * 8 + i, srow = gm & 2047;
#pragma unroll
            for (int j4 = 0; j4 < 2; ++j4) {
                int gn = n0 + tx * 8 + j4 * 4;
                int h = gn >> 6, d = gn & 63;
                float4 bi = bias ? *(const float4*)(bias + gn)
                                 : make_float4(0.f, 0.f, 0.f, 0.f);
                size_t o = ((size_t)(bb * NH + h) * S_LEN + srow) * DHD + d;
                ushort4 pk;
                pk.x = f2h(acc[i][j4 * 4 + 0] + bi.x);
                pk.y = f2h(acc[i][j4 * 4 + 1] + bi.y);
                pk.z = f2h(acc[i][j4 * 4 + 2] + bi.z);
                pk.w = f2h(acc[i][j4 * 4 + 3] + bi.w);
                *(ushort4*)(dst + o) = pk;
            }
        }
    } else {                               // VT fp16 [bh][d][s]
        unsigned short* vt = (unsigned short*)(wsb + BY_VT);
#pragma unroll
        for (int j = 0; j < 8; ++j) {
            int gn = n0 + tx * 8 + j;
            int h = gn >> 6, d = gn & 63;
            float bval = bvp[gn];
            size_t rowbase = ((size_t)(bb * NH + h) * DHD + d) * S_LEN;
#pragma unroll
            for (int i4 = 0; i4 < 2; ++i4) {
                int srow = (m0 & 2047) + ty * 8 + i4 * 4;
                ushort4 pk;
                pk.x = f2h(acc[i4 * 4 + 0][j] + bval);
                pk.y = f2h(acc[i4 * 4 + 1][j] + bval);
                pk.z = f2h(acc[i4 * 4 + 2][j] + bval);
                pk.w = f2h(acc[i4 * 4 + 3][j] + bval);
                *(ushort4*)(vt + rowbase + srow) = pk;
            }
        }
    }
}

// ---------------------------------------------------------------------------
// pos GEMM via fp16 MFMA, no LDS: raw = QV_h[2048,64] @ Pb_h[2048,64]^T, but
// scatter-stored pre-shifted: raw[q][j] -> Psh[q][j+q-2047] if j >= 2047-q,
// else Psh[q-1][j+q+1] (q>0).  Bijection onto all (q,k) except k==q+1.
// Block 256 thr = 2x2 waves, each 64x64.
// ---------------------------------------------------------------------------
__global__ __launch_bounds__(256)
void pos_gemm(const unsigned short* __restrict__ qv,
              const unsigned short* __restrict__ pb,
              unsigned short* __restrict__ psh, int head_base)
{
    const int t = threadIdx.x;
    const int wave = t >> 6, lane = t & 63;
    const int quad = lane >> 4, l16 = lane & 15;
    const int wm = wave >> 1, wn = wave & 1;
    const int z = blockIdx.z, g = head_base + z;
    const int m0 = blockIdx.y * 128 + wm * 64;
    const int n0 = blockIdx.x * 128 + wn * 64;

    const unsigned short* A = qv + (size_t)g * HEAD_ELEMS;   // [s][d]
    const unsigned short* B = pb + (size_t)g * HEAD_ELEMS;   // [s][d]
    unsigned short* out = psh + (size_t)z * SS;

    v8s af[4][2], bf[4][2];
#pragma unroll
    for (int i = 0; i < 4; ++i)
#pragma unroll
        for (int kk = 0; kk < 2; ++kk) {
            af[i][kk] = *(const v8s*)(A + (size_t)(m0 + i * 16 + l16) * DHD + kk * 32 + quad * 8);
            bf[i][kk] = *(const v8s*)(B + (size_t)(n0 + i * 16 + l16) * DHD + kk * 32 + quad * 8);
        }

#pragma unroll
    for (int i = 0; i < 4; ++i)
#pragma unroll
        for (int j = 0; j < 4; ++j) {
            v4f c = (v4f){0.f, 0.f, 0.f, 0.f};
            c = __builtin_amdgcn_mfma_f32_16x16x32_f16(af[i][0], bf[j][0], c, 0, 0, 0);
            c = __builtin_amdgcn_mfma_f32_16x16x32_f16(af[i][1], bf[j][1], c, 0, 0, 0);
#pragma unroll
            for (int reg = 0; reg < 4; ++reg) {
                int qrow = m0 + i * 16 + quad * 4 + reg;
                int jcol = n0 + j * 16 + l16;
                unsigned short val = f2h(c[reg]);
                if (jcol >= 2047 - qrow) {
                    out[(size_t)qrow * S_LEN + (jcol + qrow - 2047)] = val;
                } else if (qrow > 0) {
                    out[(size_t)(qrow - 1) * S_LEN + (jcol + qrow + 1)] = val;
                }
            }
        }
}

// ---------------------------------------------------------------------------
// Flash attention, swapped operands, split-K=4, barrier-free k-loop.
// Block 256 = 4 waves; all share q-tile [qt*16, +16); wave w owns keys
// [w*512, +512), 4 k-tiles of 128.
// QK^T: A=K-rows, B=Q-rows -> C[key=quad*4+reg + nt*16][q=l16].
// Pos: Psh[q][k] pre-shifted -> aligned ushort4 loads; k==q+1 zeroed (garbage).
// Softmax: per-lane over 32 els + shfl_xor(16,32); m/l scalar per lane (q=l16).
// P: 8 x ds_write_b64 into Sp[q=l16][key], read back as A-frag v8s.
// PV: A=P, B=V(VT rows) -> accv rows q=quad*4+reg, col d=ntd*16+l16.
// End: one barrier; wave0 4-way flash-merges and stores ctx.
// LDS 20.5 KB -> 7-8 blocks/CU.
// ---------------------------------------------------------------------------
__global__ __launch_bounds__(256, 4)
void attn_fused(const unsigned short* __restrict__ qu,
                const unsigned short* __restrict__ kdat,
                const unsigned short* __restrict__ vtg,
                const unsigned short* __restrict__ psh,
                float* __restrict__ ctx, int head_base)
{
    __shared__ unsigned short SpAll[4][2304];   // per-wave: P 16x136 / acc dump
    __shared__ float MlAll[4][128];             // per-wave: (m,l) per lane

    const int t = threadIdx.x;
    const int wave = t >> 6, lane = t & 63;
    const int quad = lane >> 4, l16 = lane & 15;
    const int z = blockIdx.x >> 7, qt = blockIdx.x & 127;
    const int g = head_base + z;
    const int q0 = qt * 16;
    const int q = q0 + l16;                     // this lane's softmax row

    const unsigned short* QU = qu   + (size_t)g * HEAD_ELEMS;   // [s][d]
    const unsigned short* Kg = kdat + (size_t)g * HEAD_ELEMS;   // [s][d]
    const unsigned short* Vg = vtg  + (size_t)g * HEAD_ELEMS;   // [d][s]
    const unsigned short* Ps = psh  + (size_t)z * SS;           // fp16 shifted
    unsigned short* Sp = &SpAll[wave][0];

    // loop-invariant Q fragments (B-operand)
    const v8s bq0 = *(const v8s*)(QU + (size_t)(q0 + l16) * DHD + quad * 8);
    const v8s bq1 = *(const v8s*)(QU + (size_t)(q0 + l16) * DHD + 32 + quad * 8);

    float m_run = -1e30f, l_run = 0.f;
    v4f accv[4];
#pragma unroll
    for (int r = 0; r < 4; ++r) accv[r] = (v4f){0.f, 0.f, 0.f, 0.f};
    const float scale = 0.04419417382415922f;   // 1/sqrt(512)
    const size_t prow = (size_t)q * S_LEN;

    for (int kt = 0; kt < 4; ++kt) {
        const int k0 = wave * 512 + kt * 128;

        // issue pos loads early (independent, aligned 8B)
        ushort4 pl[8];
#pragma unroll
        for (int nt = 0; nt < 8; ++nt)
            pl[nt] = *(const ushort4*)(Ps + prow + k0 + nt * 16 + quad * 4);

        // QK^T: C[key][q]
        v4f sacc[8];
#pragma unroll
        for (int nt = 0; nt < 8; ++nt) {
            v8s a0 = *(const v8s*)(Kg + (size_t)(k0 + nt * 16 + l16) * DHD + quad * 8);
            v8s a1 = *(const v8s*)(Kg + (size_t)(k0 + nt * 16 + l16) * DHD + 32 + quad * 8);
            v4f c = (v4f){0.f, 0.f, 0.f, 0.f};
            c = __builtin_amdgcn_mfma_f32_16x16x32_f16(a0, bq0, c, 0, 0, 0);
            c = __builtin_amdgcn_mfma_f32_16x16x32_f16(a1, bq1, c, 0, 0, 0);
            sacc[nt] = c;
        }

        // add pos (zero at k==q+1) and scale; local max
        float tm = -1e30f;
#pragma unroll
        for (int nt = 0; nt < 8; ++nt) {
            int kb = k0 + nt * 16 + quad * 4;
            const unsigned short* pv4 = (const unsigned short*)&pl[nt];
#pragma unroll
            for (int reg = 0; reg < 4; ++reg) {
                float pv = ((kb + reg) == q + 1) ? 0.f : h2f(pv4[reg]);
                sacc[nt][reg] = (sacc[nt][reg] + pv) * scale;
                tm = fmaxf(tm, sacc[nt][reg]);
            }
        }
        // cross-quad max (cols of q=l16 live in all 4 quads)
        tm = fmaxf(tm, __shfl_xor(tm, 16));
        tm = fmaxf(tm, __shfl_xor(tm, 32));
        float mn = fmaxf(m_run, tm);
        float al = __expf(m_run - mn);
        float rs = 0.f;
#pragma unroll
        for (int nt = 0; nt < 8; ++nt)
#pragma unroll
            for (int reg = 0; reg < 4; ++reg) {
                sacc[nt][reg] = __expf(sacc[nt][reg] - mn);
                rs += sacc[nt][reg];
            }
        rs += __shfl_xor(rs, 16);
        rs += __shfl_xor(rs, 32);
        l_run = l_run * al + rs;
        m_run = mn;

        // rescale acc rows (row q' = q0+quad*4+reg needs alpha of that q')
        float alr[4];
#pragma unroll
        for (int reg = 0; reg < 4; ++reg) alr[reg] = __shfl(al, quad * 4 + reg);
#pragma unroll
        for (int ntd = 0; ntd < 4; ++ntd)
#pragma unroll
            for (int reg = 0; reg < 4; ++reg) accv[ntd][reg] *= alr[reg];

        // P -> Sp[q=l16][key] as 8B packs (wave-private, in-order)
#pragma unroll
        for (int nt = 0; nt < 8; ++nt) {
            ushort4 pk;
            pk.x = f2h(sacc[nt][0]); pk.y = f2h(sacc[nt][1]);
            pk.z = f2h(sacc[nt][2]); pk.w = f2h(sacc[nt][3]);
            *(ushort4*)&Sp[l16 * 136 + nt * 16 + quad * 4] = pk;
        }

        // PV: A=P, B=V
#pragma unroll
        for (int c4 = 0; c4 < 4; ++c4) {
            v8s ap = *(const v8s*)&Sp[l16 * 136 + c4 * 32 + quad * 8];
#pragma unroll
            for (int ntd = 0; ntd < 4; ++ntd) {
                v8s bv8 = *(const v8s*)(Vg + (size_t)(ntd * 16 + l16) * S_LEN +
                                        k0 + c4 * 32 + quad * 8);
                accv[ntd] = __builtin_amdgcn_mfma_f32_16x16x32_f16(ap, bv8, accv[ntd], 0, 0, 0);
            }
        }
    }

    // dump state; wave0 merges
    MlAll[wave][lane * 2]     = m_run;
    MlAll[wave][lane * 2 + 1] = l_run;
    if (wave != 0) {
        float* accSlot = (float*)&SpAll[wave][0];
#pragma unroll
        for (int ntd = 0; ntd < 4; ++ntd)
#pragma unroll
            for (int reg = 0; reg < 4; ++reg)
                accSlot[lane * 16 + ntd * 4 + reg] = accv[ntd][reg];
    }
    __syncthreads();
    if (wave == 0) {
        const int bb = g >> 3, h = g & 7;
        float ew[4][4], inv[4];
#pragma unroll
        for (int reg = 0; reg < 4; ++reg) {
            int qi = quad * 4 + reg;           // lane qi holds (m,l) for row q0+qi
            float mw[4], lw[4];
#pragma unroll
            for (int w = 0; w < 4; ++w) {
                mw[w] = MlAll[w][qi * 2];
                lw[w] = MlAll[w][qi * 2 + 1];
            }
            float ms = fmaxf(fmaxf(mw[0], mw[1]), fmaxf(mw[2], mw[3]));
            float lt = 0.f;
#pragma unroll
            for (int w = 0; w < 4; ++w) {
                ew[reg][w] = __expf(mw[w] - ms);
                lt += lw[w] * ew[reg][w];
            }
            inv[reg] = 1.f / lt;
        }
#pragma unroll
        for (int ntd = 0; ntd < 4; ++ntd) {
#pragma unroll
            for (int reg = 0; reg < 4; ++reg) {
                float o = accv[ntd][reg] * ew[reg][0];
#pragma unroll
                for (int w = 1; w < 4; ++w) {
                    const float* slot = (const float*)&SpAll[w][0];
                    o += slot[lane * 16 + ntd * 4 + reg] * ew[reg][w];
                }
                int qq = q0 + quad * 4 + reg;
                ctx[((size_t)(bb * S_LEN + qq)) * DM + h * DHD + ntd * 16 + l16] =
                    o * inv[reg];
            }
        }
    }
}

// ---------------------------------------------------------------------------
// Output GEMM: out[4096,512] = ctx @ Wo + bo (fp32)
// ---------------------------------------------------------------------------
__global__ __launch_bounds__(256)
void out_gemm(const float* __restrict__ ca,
              const float* __restrict__ Wo, const float* __restrict__ bo,
              float* __restrict__ out)
{
    __shared__ float Ast[32][132];
    __shared__ float Bs[32][132];
    const int t = threadIdx.x;
    const int tx = t & 15, ty = t >> 4;
    const int n0 = blockIdx.x * 128, m0 = blockIdx.y * 128;

    float acc[8][8];
#pragma unroll
    for (int i = 0; i < 8; ++i)
#pragma unroll
        for (int j = 0; j < 8; ++j) acc[i][j] = 0.f;

    for (int k0 = 0; k0 < 512; k0 += 32) {
#pragma unroll
        for (int i = 0; i < 4; ++i) {
            int f = t + i * 256;
            int row = f >> 3, kq = f & 7;
            float4 a4 = *(const float4*)(ca + (size_t)(m0 + row) * 512 + k0 + kq * 4);
            Ast[kq * 4 + 0][row] = a4.x; Ast[kq * 4 + 1][row] = a4.y;
            Ast[kq * 4 + 2][row] = a4.z; Ast[kq * 4 + 3][row] = a4.w;
        }
#pragma unroll
        for (int i = 0; i < 4; ++i) {
            int f = t + i * 256;
            int row = f >> 5, c4 = f & 31;
            *(float4*)&Bs[row][c4 * 4] =
                *(const float4*)(Wo + (size_t)(k0 + row) * 512 + n0 + c4 * 4);
        }
        __syncthreads();
#pragma unroll
        for (int kc = 0; kc < 32; ++kc) {
            float a[8], b[8];
            *(float4*)&a[0] = *(const float4*)&Ast[kc][ty * 8];
            *(float4*)&a[4] = *(const float4*)&Ast[kc][ty * 8 + 4];
            *(float4*)&b[0] = *(const float4*)&Bs[kc][tx * 8];
            *(float4*)&b[4] = *(const float4*)&Bs[kc][tx * 8 + 4];
#pragma unroll
            for (int i = 0; i < 8; ++i)
#pragma unroll
                for (int j = 0; j < 8; ++j) acc[i][j] = fmaf(a[i], b[j], acc[i][j]);
        }
        __syncthreads();
    }

#pragma unroll
    for (int i = 0; i < 8; ++i) {
        int gm = m0 + ty * 8 + i;
#pragma unroll
        for (int j4 = 0; j4 < 2; ++j4) {
            int gn = n0 + tx * 8 + j4 * 4;
            float4 bi = *(const float4*)(bo + gn);
            *(float4*)(out + (size_t)gm * 512 + gn) =
                make_float4(acc[i][j4 * 4 + 0] + bi.x, acc[i][j4 * 4 + 1] + bi.y,
                            acc[i][j4 * 4 + 2] + bi.z, acc[i][j4 * 4 + 3] + bi.w);
        }
    }
}

// Fallback when ws_size is insufficient: clean mismatch instead of OOB writes.
__global__ void zero_fill(float* __restrict__ p, int n)
{
    int i = blockIdx.x * 256 + threadIdx.x;
    if (i < n) p[i] = 0.f;
}

// ---------------------------------------------------------------------------
extern "C" void kernel_launch(void* const* d_in, const int* in_sizes, int n_in,
                              void* d_out, int out_size, void* d_ws, size_t ws_size,
                              hipStream_t stream)
{
    const float* x   = (const float*)d_in[0];
    const float* pos = (const float*)d_in[1];
    const float* Wq  = (const float*)d_in[2];
    const float* bq  = (const float*)d_in[3];
    const float* Wk  = (const float*)d_in[4];
    const float* bk  = (const float*)d_in[5];
    const float* Wv  = (const float*)d_in[6];
    const float* bv  = (const float*)d_in[7];
    const float* Wp  = (const float*)d_in[8];
    const float* u   = (const float*)d_in[9];
    const float* v   = (const float*)d_in[10];
    const float* Wo  = (const float*)d_in[11];
    const float* bo  = (const float*)d_in[12];
    char* wsb  = (char*)d_ws;
    float* out = (float*)d_out;

    // Workspace guard: need BY_PSH + >=1 head of shifted pos (37.7 MB min).
    if (ws_size < (size_t)BY_PSH + PSH_HEAD_BYTES) {
        zero_fill<<<(out_size + 255) / 256, 256, 0, stream>>>(out, out_size);
        return;
    }

    // 1. projections
    proj_kernel<<<dim3(4, 32, 4), 256, 0, stream>>>(x, pos, Wq, bq, Wk, bk, Wv, bv,
                                                    Wp, u, v, wsb);

    // 2. attention in head-chunks sized to workspace
    int c = (int)((ws_size - (size_t)BY_PSH) / (size_t)PSH_HEAD_BYTES);
    if (c < 1) c = 1;
    if (c > NBH) c = NBH;

    for (int g0 = 0; g0 < NBH; g0 += c) {
        int cc = (NBH - g0 < c) ? (NBH - g0) : c;
        pos_gemm<<<dim3(16, 16, cc), 256, 0, stream>>>(
            (const unsigned short*)(wsb + BY_QV),
            (const unsigned short*)(wsb + BY_PB),
            (unsigned short*)(wsb + BY_PSH), g0);
        attn_fused<<<dim3(cc * 128), 256, 0, stream>>>(
            (const unsigned short*)(wsb + BY_QU),
            (const unsigned short*)(wsb + BY_K),
            (const unsigned short*)(wsb + BY_VT),
            (const unsigned short*)(wsb + BY_PSH),
            (float*)(wsb + BY_CTX), g0);
    }

    // 3. output projection
    out_gemm<<<dim3(4, 32, 1), 256, 0, stream>>>((const float*)(wsb + BY_CTX),
                                                 Wo, bo, out);
}